// Round 4
// 1331.562 us; speedup vs baseline: 1.0956x; 1.0956x over previous
//
#include <hip/hip_runtime.h>
#include <hip/hip_bf16.h>

#define B_  8
#define L_  4096
#define D_  1024
#define H_  16
#define MTOT (B_*L_)          // 32768
#define NFF  (4*D_)           // 4096

typedef __bf16 bf16_t;
typedef float  f32x4 __attribute__((ext_vector_type(4)));
typedef __bf16 b16x8 __attribute__((ext_vector_type(8)));
typedef __bf16 b16x4 __attribute__((ext_vector_type(4)));

// ---- workspace offsets (bytes). Weights [0,32MB), Xb [32,96MB), B-region at 96MB.
#define OFF_WQKVT ((size_t)0)                    // bf16 [3072][1024]  6 MB
#define OFF_WOT   ((size_t)6291456)              // bf16 [1024][1024]  2 MB
#define OFF_W1T   ((size_t)8388608)              // bf16 [4096][1024]  8 MB
#define OFF_W2T   ((size_t)16777216)             // bf16 [1024][4096]  8 MB
#define OFF_BQKV  ((size_t)25165824)             // fp32 [3072]
#define OFF_XB    ((size_t)33554432)             // bf16 [32768][1024] 64 MB (X+pe, later X1)
#define OFF_B     ((size_t)100663296)            // flexible region at 96 MB

// ---------------- X = bf16(X + pe) ----------------
__global__ __launch_bounds__(256) void k_add_pe(const float* __restrict__ X,
                                                const float* __restrict__ pe,
                                                bf16_t* __restrict__ Xb)
{
    size_t i  = ((size_t)blockIdx.x * 256 + threadIdx.x) * 4;
    size_t ld = i & ((size_t)L_ * D_ - 1);
    float4 x = *(const float4*)(X + i);
    float4 p = *(const float4*)(pe + ld);
    b16x4 b;
    b[0] = (bf16_t)(x.x + p.x); b[1] = (bf16_t)(x.y + p.y);
    b[2] = (bf16_t)(x.z + p.z); b[3] = (bf16_t)(x.w + p.w);
    *(b16x4*)(Xb + i) = b;
}

// ---------------- fused weight prep: 6 transposes + bias concat ----------------
__global__ __launch_bounds__(256) void k_prep(const float* __restrict__ Wq,
                                              const float* __restrict__ Wk,
                                              const float* __restrict__ Wv,
                                              const float* __restrict__ Wo,
                                              const float* __restrict__ W1,
                                              const float* __restrict__ W2,
                                              const float* __restrict__ bq,
                                              const float* __restrict__ bk,
                                              const float* __restrict__ bv,
                                              bf16_t* __restrict__ WqkvT,
                                              bf16_t* __restrict__ WoT,
                                              bf16_t* __restrict__ W1T,
                                              bf16_t* __restrict__ W2T,
                                              float* __restrict__ bqkv)
{
    const int id = blockIdx.x;
    if (id >= 12288) {                       // bias concat
        const int i = (id - 12288) * 256 + threadIdx.x;
        if (i < 1024)       bqkv[i] = bq[i];
        else if (i < 2048)  bqkv[i] = bk[i - 1024];
        else if (i < 3072)  bqkv[i] = bv[i - 2048];
        return;
    }
    const float* src; bf16_t* dst; int K, N, t;
    if (id < 4096) {
        const int w = id >> 10; t = id & 1023; K = 1024; N = 1024;
        src = (w == 0) ? Wq : (w == 1) ? Wk : (w == 2) ? Wv : Wo;
        dst = (w < 3) ? (WqkvT + (size_t)w * 1024 * 1024) : WoT;
    } else if (id < 8192) {
        t = id - 4096; K = 1024; N = 4096; src = W1; dst = W1T;
    } else {
        t = id - 8192; K = 4096; N = 1024; src = W2; dst = W2T;
    }
    const int ntiles = N >> 5;
    const int n0 = (t % ntiles) << 5;
    const int k0 = (t / ntiles) << 5;

    __shared__ float tt[32][33];
    const int tx = threadIdx.x & 31;
    const int ty = threadIdx.x >> 5;
    #pragma unroll
    for (int i = ty; i < 32; i += 8)
        tt[i][tx] = src[(size_t)(k0 + i) * N + n0 + tx];
    __syncthreads();
    #pragma unroll
    for (int i = ty; i < 32; i += 8)
        dst[(size_t)(n0 + i) * K + k0 + tx] = (bf16_t)tt[tx][i];
}

// ---------------- 256x256 8-phase bf16 GEMM (T2+T3+T4+T5) ----------------
// 512 threads = 8 waves (2M x 4N). BK=64. LDS: A0|B0|A1|B1 = 4 x 32KB = 128KB
// (dynamic). Row = 64 bf16 = 128B = 8 chunks of 16B; chunk c of row r lives in
// slot c^(r&7) (XOR swizzle, bank-conflict-free; staged by pre-swizzling the
// global source chunk so global_load_lds' linear dest is correct).
// Per iteration: 2 K-tiles, 8 phases. Phase p: {ds_read subtile, 2x
// global_load_lds, s_barrier, setprio(1), 16 MFMA, setprio(0), s_barrier}.
// Counted vmcnt(4) ONLY at end of phases 3 and 7 (never drain to 0 in-loop).
// Re-stage schedule (region <- earliest phase after its last LDS reader):
//   A1<-ph0,1 (last read prev ph6)   B0<-ph2,3 (last read ph1)
//   A0<-ph4,5 (last read ph2)        B1<-ph6,7 (last read ph5)
// vmcnt(4)@ph3 end: allows only ph2,3's B0 loads outstanding -> A1(ph0,1) and
// B1(prev ph6,7) landed before ph4 reads.  vmcnt(4)@ph7 end: allows only B1
// (ph6,7) outstanding -> A0,B0 landed before next ph0 reads.

__device__ __forceinline__ void gload_lds16(const void* g, char* lds_byte) {
    __builtin_amdgcn_global_load_lds((const __attribute__((address_space(1))) void*)g,
                                     (__attribute__((address_space(3))) void*)lds_byte,
                                     16, 0, 0);
}

#define GBAR() __builtin_amdgcn_s_barrier()
#define VM4()  asm volatile("s_waitcnt vmcnt(4)" ::: "memory")
#define PRI(x) __builtin_amdgcn_s_setprio(x)

// EPI: 0 = fp32 out, 1 = bf16 out, 2 = relu -> bf16 out
template<int EPI>
__global__ __launch_bounds__(512, 2) void k_g256(const bf16_t* __restrict__ A,
                                                 const bf16_t* __restrict__ Bt,
                                                 const float* __restrict__ bias,
                                                 void* __restrict__ Cv,
                                                 const int N, const int K)
{
    extern __shared__ char smem[];           // 128 KB: A0,B0,A1,B1
    const int tid  = threadIdx.x;
    const int wave = tid >> 6;
    const int lane = tid & 63;
    const int wm   = wave >> 2;              // 0..1
    const int wn   = wave & 3;               // 0..3

    // XCD-aware swizzle (bijective: grid always divisible by 8 here)
    const int Nt = gridDim.x, Mt = gridDim.y;
    const int lid = blockIdx.y * Nt + blockIdx.x;
    const int xcd = lid & 7;
    const int sgl = lid >> 3;
    const int bm  = xcd * (Mt >> 3) + sgl / Nt;
    const int bn  = sgl % Nt;
    const int m0 = bm * 256, n0 = bn * 256;

    // staging: thread stages row (issue*64 + tid>>3), LDS slot tid&7, so it
    // fetches global chunk (tid&7)^((tid>>3)&7).
    const int srow   = tid >> 3;
    const int schunk = (tid & 7) ^ (srow & 7);
    const bf16_t* agA = A  + (size_t)(m0 + srow) * K + schunk * 8;
    const bf16_t* bgB = Bt + (size_t)(n0 + srow) * K + schunk * 8;
    const size_t rstep = (size_t)64 * K;     // +64 rows
    const int Km1 = K - 1;                   // K is a power of two (1024/4096)
    char* ldsw = smem + wave * 1024;         // wave-uniform; HW adds lane*16

    // reader: row = base + (lane&15) + 16*mi; row&7 == lane&7.
    // K-half s, quad q=lane>>4 wants global chunk s*4+q -> slot (s*4+q)^(lane&7).
    const int q  = lane >> 4, x7 = lane & 7;
    const int sl0 = (q ^ x7) << 3;
    const int sl1 = ((4 + q) ^ x7) << 3;
    const bf16_t* A0p = (const bf16_t*)(smem)         + (wm * 128 + (lane & 15)) * 64;
    const bf16_t* B0p = (const bf16_t*)(smem + 32768) + (wn * 64  + (lane & 15)) * 64;
    const bf16_t* A1p = (const bf16_t*)(smem + 65536) + (wm * 128 + (lane & 15)) * 64;
    const bf16_t* B1p = (const bf16_t*)(smem + 98304) + (wn * 64  + (lane & 15)) * 64;

    f32x4 acc[8][4] = {};
    b16x8 aF[8], bF[8];      // aF: current m-half (4 mi x 2 kh); bF: all 4 ni x 2 kh

#define STG2(gb, koff, ldsoff, pair) \
    gload_lds16(gb + (size_t)(2*(pair)+0)*rstep + (koff), ldsw + (ldsoff) + (2*(pair)+0)*8192); \
    gload_lds16(gb + (size_t)(2*(pair)+1)*rstep + (koff), ldsw + (ldsoff) + (2*(pair)+1)*8192)
#define RDA(P, mh) { _Pragma("unroll") for (int ml = 0; ml < 4; ++ml) { \
    aF[2*ml+0] = *(const b16x8*)((P) + (mh)*4096 + ml*1024 + sl0); \
    aF[2*ml+1] = *(const b16x8*)((P) + (mh)*4096 + ml*1024 + sl1); } }
#define RDB(P, nh) { _Pragma("unroll") for (int nl = 0; nl < 2; ++nl) { \
    bF[2*((nh)*2+nl)+0] = *(const b16x8*)((P) + ((nh)*2+nl)*1024 + sl0); \
    bF[2*((nh)*2+nl)+1] = *(const b16x8*)((P) + ((nh)*2+nl)*1024 + sl1); } }
#define MM(mh, nh) { _Pragma("unroll") for (int ml = 0; ml < 4; ++ml) \
    _Pragma("unroll") for (int nl = 0; nl < 2; ++nl) { \
        f32x4& c = acc[(mh)*4+ml][(nh)*2+nl]; \
        c = __builtin_amdgcn_mfma_f32_16x16x32_bf16(aF[2*ml+0], bF[2*((nh)*2+nl)+0], c, 0, 0, 0); \
        c = __builtin_amdgcn_mfma_f32_16x16x32_bf16(aF[2*ml+1], bF[2*((nh)*2+nl)+1], c, 0, 0, 0); } }

    // prologue: tile0 -> A0,B0; tile1's B -> B1 (tile1's A comes in ph0,1)
    #pragma unroll
    for (int i = 0; i < 4; ++i) gload_lds16(agA + (size_t)i * rstep,      ldsw + 0     + i * 8192);
    #pragma unroll
    for (int i = 0; i < 4; ++i) gload_lds16(bgB + (size_t)i * rstep,      ldsw + 32768 + i * 8192);
    #pragma unroll
    for (int i = 0; i < 4; ++i) gload_lds16(bgB + (size_t)i * rstep + 64, ldsw + 98304 + i * 8192);
    VM4();      // allow B1 x4 in flight; A0,B0 landed
    GBAR();

    int kb = 0;
    const int niter = K >> 7;                // 2 K-tiles per iteration
    for (int it = 0; it < niter; ++it) {
        const int k1 = (kb +  64) & Km1;     // tile 2I+1 (A1)
        const int k2 = (kb + 128) & Km1;     // tile 2I+2 (B0, A0)
        const int k3 = (kb + 192) & Km1;     // tile 2I+3 (B1)
        // ph0: Q(m0,n0) of buf0
        RDA(A0p, 0); RDB(B0p, 0); STG2(agA, k1, 65536, 0);
        GBAR(); PRI(1); MM(0, 0); PRI(0); GBAR();
        // ph1: Q(m0,n1)
        RDB(B0p, 1);              STG2(agA, k1, 65536, 1);
        GBAR(); PRI(1); MM(0, 1); PRI(0); GBAR();
        // ph2: Q(m1,n1)
        RDA(A0p, 1);              STG2(bgB, k2, 32768, 0);
        GBAR(); PRI(1); MM(1, 1); PRI(0); GBAR();
        // ph3: Q(m1,n0) (all frags live; 0 ds_reads)
                                  STG2(bgB, k2, 32768, 1);
        GBAR(); PRI(1); MM(1, 0); PRI(0); VM4(); GBAR();
        // ph4: Q(m0,n0) of buf1
        RDA(A1p, 0); RDB(B1p, 0); STG2(agA, k2, 0, 0);
        GBAR(); PRI(1); MM(0, 0); PRI(0); GBAR();
        // ph5: Q(m0,n1)
        RDB(B1p, 1);              STG2(agA, k2, 0, 1);
        GBAR(); PRI(1); MM(0, 1); PRI(0); GBAR();
        // ph6: Q(m1,n1)
        RDA(A1p, 1);              STG2(bgB, k3, 98304, 0);
        GBAR(); PRI(1); MM(1, 1); PRI(0); GBAR();
        // ph7: Q(m1,n0)
                                  STG2(bgB, k3, 98304, 1);
        GBAR(); PRI(1); MM(1, 0); PRI(0); VM4(); GBAR();
        kb = (kb + 128) & Km1;               // last iter wraps: redundant, safe
    }
    asm volatile("s_waitcnt vmcnt(0)" ::: "memory");

    // epilogue (same C/D mapping as verified 128^2 kernel)
    const int rbase = m0 + wm * 128 + ((lane >> 4) << 2);
    const int cbase = n0 + wn * 64 + (lane & 15);
    #pragma unroll
    for (int mi = 0; mi < 8; ++mi) {
        #pragma unroll
        for (int ni = 0; ni < 4; ++ni) {
            const int col = cbase + ni * 16;
            const float bb = bias[col];
            #pragma unroll
            for (int r = 0; r < 4; ++r) {
                const int rowg = rbase + mi * 16 + r;
                float v = acc[mi][ni][r] + bb;
                if (EPI == 2) v = fmaxf(v, 0.0f);
                if (EPI == 0) ((float*)Cv)[(size_t)rowg * N + col] = v;
                else          ((bf16_t*)Cv)[(size_t)rowg * N + col] = (bf16_t)v;
            }
        }
    }
#undef STG2
#undef RDA
#undef RDB
#undef MM
}

// ---------------- window-3 attention over a chunk of whole batches ----------------
__global__ __launch_bounds__(256) void k_attn(const bf16_t* __restrict__ QKV, // [rows][3072]
                                              const unsigned char* __restrict__ mask, // [rows]
                                              bf16_t* __restrict__ ctx)       // [rows][1024]
{
    const int wid  = (blockIdx.x << 2) + (threadIdx.x >> 6);
    const int lane = threadIdx.x & 63;
    const int h    = wid & (H_ - 1);
    const int l    = wid >> 4;           // chunk-local row
    const int lb   = l & (L_ - 1);       // batch-local position (chunks are whole batches)

    const float qv = (float)QKV[(size_t)l * 3072 + h * 64 + lane];
    float sc[3], vv[3];
    bool  ok[3];
    #pragma unroll
    for (int w = 0; w < 3; ++w) {
        const int d   = w - 1;
        const bool valid = (unsigned)(lb + d) < (unsigned)L_;
        const int dc  = valid ? d : 0;
        const size_t rb = (size_t)(l + dc) * 3072 + h * 64 + lane;
        const float kk = (float)QKV[rb + 1024];
        vv[w] = (float)QKV[rb + 2048];
        ok[w] = valid && (mask[l + dc] == 0);
        sc[w] = qv * kk;
    }
    #pragma unroll
    for (int off = 32; off; off >>= 1) {
        sc[0] += __shfl_xor(sc[0], off);
        sc[1] += __shfl_xor(sc[1], off);
        sc[2] += __shfl_xor(sc[2], off);
    }
    const float s0 = ok[0] ? sc[0] * 0.125f : -1e30f;
    const float s1 = ok[1] ? sc[1] * 0.125f : -1e30f;
    const float s2 = ok[2] ? sc[2] * 0.125f : -1e30f;
    const float mx = fmaxf(s0, fmaxf(s1, s2));
    const float e0 = __expf(s0 - mx), e1 = __expf(s1 - mx), e2 = __expf(s2 - mx);
    const float inv = 1.0f / (e0 + e1 + e2);
    const float o = (e0 * vv[0] + e1 * vv[1] + e2 * vv[2]) * inv;
    ctx[(size_t)l * 1024 + h * 64 + lane] = (bf16_t)o;
}

// ---------------- residual(bf16) + Y(fp32) -> layernorm ----------------
template<int FINAL>
__global__ __launch_bounds__(256) void k_res_ln(const bf16_t* __restrict__ Xres,
                                                const float* __restrict__ Y,
                                                const float* __restrict__ g,
                                                const float* __restrict__ beta,
                                                bf16_t* __restrict__ outB,
                                                float* __restrict__ outF)
{
    const int row = blockIdx.x;
    const int tid = threadIdx.x;
    const size_t base = (size_t)row * D_ + tid * 4;
    b16x4  xr = *(const b16x4*)(Xres + base);
    float4 y  = *(const float4*)(Y + base);
    const float t0 = (float)xr[0] + y.x, t1 = (float)xr[1] + y.y;
    const float t2 = (float)xr[2] + y.z, t3 = (float)xr[3] + y.w;
    float s = t0 + t1 + t2 + t3;
    float qq = t0*t0 + t1*t1 + t2*t2 + t3*t3;
    #pragma unroll
    for (int off = 32; off; off >>= 1) {
        s  += __shfl_xor(s, off);
        qq += __shfl_xor(qq, off);
    }
    __shared__ float red[8];
    const int wv = tid >> 6, ln = tid & 63;
    if (ln == 0) { red[wv] = s; red[wv + 4] = qq; }
    __syncthreads();
    s  = red[0] + red[1] + red[2] + red[3];
    qq = red[4] + red[5] + red[6] + red[7];
    const float mean = s * (1.0f / D_);
    const float var  = qq * (1.0f / D_) - mean * mean;
    const float rs   = rsqrtf(var + 1e-5f);
    const int c = tid * 4;
    float4 gv = *(const float4*)(g + c);
    float4 bv = *(const float4*)(beta + c);
    float o0 = (t0 - mean) * rs * gv.x + bv.x;
    float o1 = (t1 - mean) * rs * gv.y + bv.y;
    float o2 = (t2 - mean) * rs * gv.z + bv.z;
    float o3 = (t3 - mean) * rs * gv.w + bv.w;
    if (FINAL) {
        float4 o; o.x = o0; o.y = o1; o.z = o2; o.w = o3;
        *(float4*)(outF + base) = o;
    } else {
        b16x4 b; b[0] = (bf16_t)o0; b[1] = (bf16_t)o1; b[2] = (bf16_t)o2; b[3] = (bf16_t)o3;
        *(b16x4*)(outB + base) = b;
    }
}

extern "C" void kernel_launch(void* const* d_in, const int* in_sizes, int n_in,
                              void* d_out, int out_size, void* d_ws, size_t ws_size,
                              hipStream_t stream)
{
    const float* X    = (const float*)d_in[0];
    const unsigned char* mask = (const unsigned char*)d_in[1];
    const float* pe   = (const float*)d_in[2];
    const float* Wq   = (const float*)d_in[3];
    const float* Wk   = (const float*)d_in[4];
    const float* Wv   = (const float*)d_in[5];
    const float* bq   = (const float*)d_in[6];
    const float* bk   = (const float*)d_in[7];
    const float* bv   = (const float*)d_in[8];
    const float* Wo   = (const float*)d_in[9];
    const float* bo   = (const float*)d_in[10];
    const float* g1   = (const float*)d_in[11];
    const float* be1  = (const float*)d_in[12];
    const float* W1   = (const float*)d_in[13];
    const float* b1   = (const float*)d_in[14];
    const float* W2   = (const float*)d_in[15];
    const float* b2   = (const float*)d_in[16];
    const float* g2   = (const float*)d_in[17];
    const float* be2  = (const float*)d_in[18];

    // one-time: allow 128 KB dynamic LDS on the GEMM instantiations
    static int s_attr = [](){
        (void)hipFuncSetAttribute(reinterpret_cast<const void*>(&k_g256<0>),
                                  hipFuncAttributeMaxDynamicSharedMemorySize, 131072);
        (void)hipFuncSetAttribute(reinterpret_cast<const void*>(&k_g256<1>),
                                  hipFuncAttributeMaxDynamicSharedMemorySize, 131072);
        (void)hipFuncSetAttribute(reinterpret_cast<const void*>(&k_g256<2>),
                                  hipFuncAttributeMaxDynamicSharedMemorySize, 131072);
        return 0;
    }();
    (void)s_attr;

    char* ws = (char*)d_ws;
    bf16_t* WqkvT = (bf16_t*)(ws + OFF_WQKVT);
    bf16_t* WoT   = (bf16_t*)(ws + OFF_WOT);
    bf16_t* W1T   = (bf16_t*)(ws + OFF_W1T);
    bf16_t* W2T   = (bf16_t*)(ws + OFF_W2T);
    float*  bqkv  = (float*) (ws + OFF_BQKV);
    bf16_t* Xb    = (bf16_t*)(ws + OFF_XB);
    float*  Y     = (float*)d_out;            // d_out doubles as fp32 GEMM-out scratch

    const bool big = ws_size >= (size_t)234881024;

    // 1. Xb = bf16(X + pe)
    k_add_pe<<<MTOT * D_ / 1024, 256, 0, stream>>>(X, pe, Xb);

    // 2. fused weight prep
    k_prep<<<12300, 256, 0, stream>>>(Wq, Wk, Wv, Wo, W1, W2, bq, bk, bv,
                                      WqkvT, WoT, W1T, W2T, bqkv);

    if (big) {
        bf16_t* ctx  = (bf16_t*)(ws + OFF_B);              // 64 MB [96,160)
        bf16_t* qkvc = (bf16_t*)(ws + OFF_B + 67108864);   // 50 MB [160,210.3)
        // 3. QKV + attention in 2-batch chunks (8192 rows)
        for (int c = 0; c < 4; ++c) {
            const size_t r0 = (size_t)c * 8192;
            k_g256<1><<<dim3(3072/256, 8192/256), 512, 131072, stream>>>(
                Xb + r0*D_, WqkvT, bqkv, qkvc, 3072, 1024);
            k_attn<<<8192*H_/4, 256, 0, stream>>>(qkvc, mask + r0, ctx + r0*D_);
        }
        // 4. Y = ctx @ Wo + bo (fp32, into d_out)
        k_g256<0><<<dim3(1024/256, MTOT/256), 512, 131072, stream>>>(ctx, WoT, bo, Y, 1024, 1024);
        // 5. X1 = LN(Xb + Y) -> Xb (in-place bf16)
        k_res_ln<0><<<MTOT, 256, 0, stream>>>(Xb, Y, g1, be1, Xb, nullptr);
        // 6. FFN in two 16K-row chunks
        bf16_t* hb = (bf16_t*)(ws + OFF_B);                // 128 MB [96,224)
        for (int c = 0; c < 2; ++c) {
            const size_t r0 = (size_t)c * 16384;
            k_g256<2><<<dim3(NFF/256, 16384/256), 512, 131072, stream>>>(
                Xb + r0*D_, W1T, b1, hb, NFF, 1024);
            k_g256<0><<<dim3(1024/256, 16384/256), 512, 131072, stream>>>(
                hb, W2T, b2, Y + r0*D_, 1024, NFF);
        }
        // 7. out = LN(X1 + Y) -> fp32 d_out (in-place over Y)
        k_res_ln<1><<<MTOT, 256, 0, stream>>>(Xb, Y, g2, be2, nullptr, (float*)d_out);
    } else {
        bf16_t* qkvc = (bf16_t*)(ws + OFF_B);              // 24 MB [96,120)
        bf16_t* ctxc = (bf16_t*)(ws + OFF_B + 25165824);   //  8 MB [120,128)
        for (int b = 0; b < B_; ++b) {
            const size_t r0 = (size_t)b * L_;
            k_g256<1><<<dim3(3072/256, L_/256), 512, 131072, stream>>>(
                Xb + r0*D_, WqkvT, bqkv, qkvc, 3072, 1024);
            k_attn<<<L_*H_/4, 256, 0, stream>>>(qkvc, mask + r0, ctxc);
            k_g256<0><<<dim3(1024/256, L_/256), 512, 131072, stream>>>(
                ctxc, WoT, bo, Y + r0*D_, 1024, 1024);
        }
        k_res_ln<0><<<MTOT, 256, 0, stream>>>(Xb, Y, g1, be1, Xb, nullptr);
        bf16_t* hb = (bf16_t*)(ws + OFF_B);                // 32 MB [96,128)
        for (int c = 0; c < 8; ++c) {
            const size_t r0 = (size_t)c * L_;
            k_g256<2><<<dim3(NFF/256, L_/256), 512, 131072, stream>>>(
                Xb + r0*D_, W1T, b1, hb, NFF, 1024);
            k_g256<0><<<dim3(1024/256, L_/256), 512, 131072, stream>>>(
                hb, W2T, b2, Y + r0*D_, 1024, NFF);
        }
        k_res_ln<1><<<MTOT, 256, 0, stream>>>(Xb, Y, g2, be2, nullptr, (float*)d_out);
    }
}

// Round 5
// 1322.605 us; speedup vs baseline: 1.1030x; 1.0068x over previous
//
#include <hip/hip_runtime.h>
#include <hip/hip_bf16.h>

#define B_  8
#define L_  4096
#define D_  1024
#define H_  16
#define MTOT (B_*L_)          // 32768
#define NFF  (4*D_)           // 4096

typedef __bf16 bf16_t;
typedef float  f32x4 __attribute__((ext_vector_type(4)));
typedef __bf16 b16x8 __attribute__((ext_vector_type(8)));
typedef __bf16 b16x4 __attribute__((ext_vector_type(4)));

// ---- workspace offsets (bytes). Weights [0,32MB), Xb [32,96MB), B-region at 96MB.
#define OFF_WQKVT ((size_t)0)                    // bf16 [3072][1024]  6 MB
#define OFF_WOT   ((size_t)6291456)              // bf16 [1024][1024]  2 MB
#define OFF_W1T   ((size_t)8388608)              // bf16 [4096][1024]  8 MB
#define OFF_W2T   ((size_t)16777216)             // bf16 [1024][4096]  8 MB
#define OFF_BQKV  ((size_t)25165824)             // fp32 [3072]
#define OFF_XB    ((size_t)33554432)             // bf16 [32768][1024] 64 MB (X+pe, later X1)
#define OFF_B     ((size_t)100663296)            // flexible region at 96 MB

// ---------------- X = bf16(X + pe) ----------------
__global__ __launch_bounds__(256) void k_add_pe(const float* __restrict__ X,
                                                const float* __restrict__ pe,
                                                bf16_t* __restrict__ Xb)
{
    size_t i  = ((size_t)blockIdx.x * 256 + threadIdx.x) * 4;
    size_t ld = i & ((size_t)L_ * D_ - 1);
    float4 x = *(const float4*)(X + i);
    float4 p = *(const float4*)(pe + ld);
    b16x4 b;
    b[0] = (bf16_t)(x.x + p.x); b[1] = (bf16_t)(x.y + p.y);
    b[2] = (bf16_t)(x.z + p.z); b[3] = (bf16_t)(x.w + p.w);
    *(b16x4*)(Xb + i) = b;
}

// ---------------- fused weight prep: 6 transposes + bias concat ----------------
__global__ __launch_bounds__(256) void k_prep(const float* __restrict__ Wq,
                                              const float* __restrict__ Wk,
                                              const float* __restrict__ Wv,
                                              const float* __restrict__ Wo,
                                              const float* __restrict__ W1,
                                              const float* __restrict__ W2,
                                              const float* __restrict__ bq,
                                              const float* __restrict__ bk,
                                              const float* __restrict__ bv,
                                              bf16_t* __restrict__ WqkvT,
                                              bf16_t* __restrict__ WoT,
                                              bf16_t* __restrict__ W1T,
                                              bf16_t* __restrict__ W2T,
                                              float* __restrict__ bqkv)
{
    const int id = blockIdx.x;
    if (id >= 12288) {                       // bias concat
        const int i = (id - 12288) * 256 + threadIdx.x;
        if (i < 1024)       bqkv[i] = bq[i];
        else if (i < 2048)  bqkv[i] = bk[i - 1024];
        else if (i < 3072)  bqkv[i] = bv[i - 2048];
        return;
    }
    const float* src; bf16_t* dst; int K, N, t;
    if (id < 4096) {
        const int w = id >> 10; t = id & 1023; K = 1024; N = 1024;
        src = (w == 0) ? Wq : (w == 1) ? Wk : (w == 2) ? Wv : Wo;
        dst = (w < 3) ? (WqkvT + (size_t)w * 1024 * 1024) : WoT;
    } else if (id < 8192) {
        t = id - 4096; K = 1024; N = 4096; src = W1; dst = W1T;
    } else {
        t = id - 8192; K = 4096; N = 1024; src = W2; dst = W2T;
    }
    const int ntiles = N >> 5;
    const int n0 = (t % ntiles) << 5;
    const int k0 = (t / ntiles) << 5;

    __shared__ float tt[32][33];
    const int tx = threadIdx.x & 31;
    const int ty = threadIdx.x >> 5;
    #pragma unroll
    for (int i = ty; i < 32; i += 8)
        tt[i][tx] = src[(size_t)(k0 + i) * N + n0 + tx];
    __syncthreads();
    #pragma unroll
    for (int i = ty; i < 32; i += 8)
        dst[(size_t)(n0 + i) * K + k0 + tx] = (bf16_t)tt[tx][i];
}

// ---------------- 256x256 8-phase bf16 GEMM, reads pipelined 1 phase ahead ----
// 512 threads = 8 waves (2M x 4N). BK=64. LDS: A0|B0|A1|B1 = 4 x 32KB = 128KB.
// XOR swizzle as before (slot c^(r&7)); bank-conflict-free (measured 0).
//
// R4 post-mortem: per-phase [ds_read burst ~576cy][MFMA burst ~621cy]
// serialized (MfmaUtil 40%). Fix: each phase issues the NEXT phase's ds_reads
// before its MFMA cluster; MFMA consumes regs read in the PREVIOUS phase.
// Double fragment sets: aFs[mh][8], bFs[buf][8] (all static indices).
//
// Staging (unchanged): ph0,1:A1  ph2,3:B0  ph4,5:A0  ph6,7:B1.
// Reads issued at phase p (for p+1's MFMA):
//   ph0: bFs0.nh1   ph1: aFs1<-A0.mh1  ph2: -           ph3: aFs0<-A1.mh0 + bFs1.nh0
//   ph4: bFs1.nh1   ph5: aFs1<-A1.mh1  ph6: -           ph7: aFs0<-A0.mh0 + bFs0.nh0
// vmcnt(2) at END of ph2 and ph6 (was vmcnt(4)@ph3/ph7):
//   @ph2: outstanding <=10 {prevB1(4),A1(4),B0ab(2)}; wait->2 leaves B0ab =>
//         A1 + prev-B1 landed; + barrier => ph3's reads of A1/B1 are safe.
//   @ph6: outstanding <=10 {B0ab rem(2),B0cd(2),A0(4),B1ab(2)}; wait->2 leaves
//         B1ab => A0 + B0 landed; + barrier => ph7's reads of A0/B0 are safe.
// Write-after-read: each region's last read is forced complete by the consumer
// phase's compiler-emitted lgkmcnt (before that phase's exit barrier), which
// precedes the re-stage issue by >=1 barrier. lgkmcnt stays compiler-managed.

__device__ __forceinline__ void gload_lds16(const void* g, char* lds_byte) {
    __builtin_amdgcn_global_load_lds((const __attribute__((address_space(1))) void*)g,
                                     (__attribute__((address_space(3))) void*)lds_byte,
                                     16, 0, 0);
}

#define GBAR() __builtin_amdgcn_s_barrier()
#define VM4()  asm volatile("s_waitcnt vmcnt(4)" ::: "memory")
#define VM2()  asm volatile("s_waitcnt vmcnt(2)" ::: "memory")
#define PRI(x) __builtin_amdgcn_s_setprio(x)

// EPI: 0 = fp32 out, 1 = bf16 out, 2 = relu -> bf16 out
template<int EPI>
__global__ __launch_bounds__(512, 2) void k_g256(const bf16_t* __restrict__ A,
                                                 const bf16_t* __restrict__ Bt,
                                                 const float* __restrict__ bias,
                                                 void* __restrict__ Cv,
                                                 const int N, const int K)
{
    extern __shared__ char smem[];           // 128 KB: A0,B0,A1,B1
    const int tid  = threadIdx.x;
    const int wave = tid >> 6;
    const int lane = tid & 63;
    const int wm   = wave >> 2;              // 0..1
    const int wn   = wave & 3;               // 0..3

    // XCD-aware swizzle (bijective: grid always divisible by 8 here)
    const int Nt = gridDim.x, Mt = gridDim.y;
    const int lid = blockIdx.y * Nt + blockIdx.x;
    const int xcd = lid & 7;
    const int sgl = lid >> 3;
    const int bm  = xcd * (Mt >> 3) + sgl / Nt;
    const int bn  = sgl % Nt;
    const int m0 = bm * 256, n0 = bn * 256;

    // staging: thread stages row (issue*64 + tid>>3), LDS slot tid&7, so it
    // fetches global chunk (tid&7)^((tid>>3)&7).
    const int srow   = tid >> 3;
    const int schunk = (tid & 7) ^ (srow & 7);
    const bf16_t* agA = A  + (size_t)(m0 + srow) * K + schunk * 8;
    const bf16_t* bgB = Bt + (size_t)(n0 + srow) * K + schunk * 8;
    const size_t rstep = (size_t)64 * K;     // +64 rows
    const int Km1 = K - 1;                   // K is a power of two (1024/4096)
    char* ldsw = smem + wave * 1024;         // wave-uniform; HW adds lane*16

    // reader: row = base + (lane&15) + 16*mi; row&7 == lane&7.
    // K-half s, quad q=lane>>4 wants global chunk s*4+q -> slot (s*4+q)^(lane&7).
    const int q  = lane >> 4, x7 = lane & 7;
    const int sl0 = (q ^ x7) << 3;
    const int sl1 = ((4 + q) ^ x7) << 3;
    const bf16_t* A0p = (const bf16_t*)(smem)         + (wm * 128 + (lane & 15)) * 64;
    const bf16_t* B0p = (const bf16_t*)(smem + 32768) + (wn * 64  + (lane & 15)) * 64;
    const bf16_t* A1p = (const bf16_t*)(smem + 65536) + (wm * 128 + (lane & 15)) * 64;
    const bf16_t* B1p = (const bf16_t*)(smem + 98304) + (wn * 64  + (lane & 15)) * 64;

    f32x4 acc[8][4] = {};
    b16x8 aFs[2][8];   // [mh][2*ml+kh]
    b16x8 bFs[2][8];   // [buf][2*(nh*2+nl)+kh]

#define STG2(gb, koff, ldsoff, pair) \
    gload_lds16(gb + (size_t)(2*(pair)+0)*rstep + (koff), ldsw + (ldsoff) + (2*(pair)+0)*8192); \
    gload_lds16(gb + (size_t)(2*(pair)+1)*rstep + (koff), ldsw + (ldsoff) + (2*(pair)+1)*8192)
#define RDA(P, mh) { _Pragma("unroll") for (int ml = 0; ml < 4; ++ml) { \
    aFs[mh][2*ml+0] = *(const b16x8*)((P) + (mh)*4096 + ml*1024 + sl0); \
    aFs[mh][2*ml+1] = *(const b16x8*)((P) + (mh)*4096 + ml*1024 + sl1); } }
#define RDB(P, bufi, nh) { _Pragma("unroll") for (int nl = 0; nl < 2; ++nl) { \
    bFs[bufi][2*((nh)*2+nl)+0] = *(const b16x8*)((P) + ((nh)*2+nl)*1024 + sl0); \
    bFs[bufi][2*((nh)*2+nl)+1] = *(const b16x8*)((P) + ((nh)*2+nl)*1024 + sl1); } }
#define MM(bufi, mh, nh) { _Pragma("unroll") for (int ml = 0; ml < 4; ++ml) \
    _Pragma("unroll") for (int nl = 0; nl < 2; ++nl) { \
        f32x4& c = acc[(mh)*4+ml][(nh)*2+nl]; \
        c = __builtin_amdgcn_mfma_f32_16x16x32_bf16(aFs[mh][2*ml+0], bFs[bufi][2*((nh)*2+nl)+0], c, 0, 0, 0); \
        c = __builtin_amdgcn_mfma_f32_16x16x32_bf16(aFs[mh][2*ml+1], bFs[bufi][2*((nh)*2+nl)+1], c, 0, 0, 0); } }

    // prologue: tile0 -> A0,B0; tile1's B -> B1 (tile1's A comes in ph0,1)
    #pragma unroll
    for (int i = 0; i < 4; ++i) gload_lds16(agA + (size_t)i * rstep,      ldsw + 0     + i * 8192);
    #pragma unroll
    for (int i = 0; i < 4; ++i) gload_lds16(bgB + (size_t)i * rstep,      ldsw + 32768 + i * 8192);
    #pragma unroll
    for (int i = 0; i < 4; ++i) gload_lds16(bgB + (size_t)i * rstep + 64, ldsw + 98304 + i * 8192);
    VM4();      // allow B1 x4 in flight; A0,B0 landed
    GBAR();
    // initial reads for ph0 (the "prev-ph7" reads)
    RDA(A0p, 0); RDB(B0p, 0, 0);

    int kb = 0;
    const int niter = K >> 7;                // 2 K-tiles per iteration
    for (int it = 0; it < niter; ++it) {
        const int k1 = (kb +  64) & Km1;     // tile 2I+1 (A1)
        const int k2 = (kb + 128) & Km1;     // tile 2I+2 (B0, A0)
        const int k3 = (kb + 192) & Km1;     // tile 2I+3 (B1)
        // ph0: MFMA Q(0,0) buf0; read ph1's B0.nh1
        RDB(B0p, 0, 1);              STG2(agA, k1, 65536, 0);
        GBAR(); PRI(1); MM(0, 0, 0); PRI(0); GBAR();
        // ph1: MFMA Q(0,1) buf0; read ph2's A0.mh1
        RDA(A0p, 1);                 STG2(agA, k1, 65536, 1);
        GBAR(); PRI(1); MM(0, 0, 1); PRI(0); GBAR();
        // ph2: MFMA Q(1,1) buf0; no reads; vmcnt(2) -> A1 + prev-B1 landed
                                     STG2(bgB, k2, 32768, 0);
        GBAR(); PRI(1); MM(0, 1, 1); PRI(0); VM2(); GBAR();
        // ph3: MFMA Q(1,0) buf0; read ph4's A1.mh0 + B1.nh0
        RDA(A1p, 0); RDB(B1p, 1, 0); STG2(bgB, k2, 32768, 1);
        GBAR(); PRI(1); MM(0, 1, 0); PRI(0); GBAR();
        // ph4: MFMA Q(0,0) buf1; read ph5's B1.nh1
        RDB(B1p, 1, 1);              STG2(agA, k2, 0, 0);
        GBAR(); PRI(1); MM(1, 0, 0); PRI(0); GBAR();
        // ph5: MFMA Q(0,1) buf1; read ph6's A1.mh1
        RDA(A1p, 1);                 STG2(agA, k2, 0, 1);
        GBAR(); PRI(1); MM(1, 0, 1); PRI(0); GBAR();
        // ph6: MFMA Q(1,1) buf1; no reads; vmcnt(2) -> A0 + B0 landed
                                     STG2(bgB, k3, 98304, 0);
        GBAR(); PRI(1); MM(1, 1, 1); PRI(0); VM2(); GBAR();
        // ph7: MFMA Q(1,0) buf1; read next-ph0's A0.mh0 + B0.nh0
        RDA(A0p, 0); RDB(B0p, 0, 0); STG2(bgB, k3, 98304, 1);
        GBAR(); PRI(1); MM(1, 1, 0); PRI(0); GBAR();
        kb = (kb + 128) & Km1;               // last iter wraps: redundant, safe
    }
    asm volatile("s_waitcnt vmcnt(0)" ::: "memory");

    // epilogue (same C/D mapping as verified 128^2 kernel)
    const int rbase = m0 + wm * 128 + ((lane >> 4) << 2);
    const int cbase = n0 + wn * 64 + (lane & 15);
    #pragma unroll
    for (int mi = 0; mi < 8; ++mi) {
        #pragma unroll
        for (int ni = 0; ni < 4; ++ni) {
            const int col = cbase + ni * 16;
            const float bb = bias[col];
            #pragma unroll
            for (int r = 0; r < 4; ++r) {
                const int rowg = rbase + mi * 16 + r;
                float v = acc[mi][ni][r] + bb;
                if (EPI == 2) v = fmaxf(v, 0.0f);
                if (EPI == 0) ((float*)Cv)[(size_t)rowg * N + col] = v;
                else          ((bf16_t*)Cv)[(size_t)rowg * N + col] = (bf16_t)v;
            }
        }
    }
#undef STG2
#undef RDA
#undef RDB
#undef MM
}

// ---------------- window-3 attention over a chunk of whole batches ----------------
__global__ __launch_bounds__(256) void k_attn(const bf16_t* __restrict__ QKV, // [rows][3072]
                                              const unsigned char* __restrict__ mask, // [rows]
                                              bf16_t* __restrict__ ctx)       // [rows][1024]
{
    const int wid  = (blockIdx.x << 2) + (threadIdx.x >> 6);
    const int lane = threadIdx.x & 63;
    const int h    = wid & (H_ - 1);
    const int l    = wid >> 4;           // chunk-local row
    const int lb   = l & (L_ - 1);       // batch-local position (chunks are whole batches)

    const float qv = (float)QKV[(size_t)l * 3072 + h * 64 + lane];
    float sc[3], vv[3];
    bool  ok[3];
    #pragma unroll
    for (int w = 0; w < 3; ++w) {
        const int d   = w - 1;
        const bool valid = (unsigned)(lb + d) < (unsigned)L_;
        const int dc  = valid ? d : 0;
        const size_t rb = (size_t)(l + dc) * 3072 + h * 64 + lane;
        const float kk = (float)QKV[rb + 1024];
        vv[w] = (float)QKV[rb + 2048];
        ok[w] = valid && (mask[l + dc] == 0);
        sc[w] = qv * kk;
    }
    #pragma unroll
    for (int off = 32; off; off >>= 1) {
        sc[0] += __shfl_xor(sc[0], off);
        sc[1] += __shfl_xor(sc[1], off);
        sc[2] += __shfl_xor(sc[2], off);
    }
    const float s0 = ok[0] ? sc[0] * 0.125f : -1e30f;
    const float s1 = ok[1] ? sc[1] * 0.125f : -1e30f;
    const float s2 = ok[2] ? sc[2] * 0.125f : -1e30f;
    const float mx = fmaxf(s0, fmaxf(s1, s2));
    const float e0 = __expf(s0 - mx), e1 = __expf(s1 - mx), e2 = __expf(s2 - mx);
    const float inv = 1.0f / (e0 + e1 + e2);
    const float o = (e0 * vv[0] + e1 * vv[1] + e2 * vv[2]) * inv;
    ctx[(size_t)l * 1024 + h * 64 + lane] = (bf16_t)o;
}

// ---------------- residual(bf16) + Y(fp32) -> layernorm ----------------
template<int FINAL>
__global__ __launch_bounds__(256) void k_res_ln(const bf16_t* __restrict__ Xres,
                                                const float* __restrict__ Y,
                                                const float* __restrict__ g,
                                                const float* __restrict__ beta,
                                                bf16_t* __restrict__ outB,
                                                float* __restrict__ outF)
{
    const int row = blockIdx.x;
    const int tid = threadIdx.x;
    const size_t base = (size_t)row * D_ + tid * 4;
    b16x4  xr = *(const b16x4*)(Xres + base);
    float4 y  = *(const float4*)(Y + base);
    const float t0 = (float)xr[0] + y.x, t1 = (float)xr[1] + y.y;
    const float t2 = (float)xr[2] + y.z, t3 = (float)xr[3] + y.w;
    float s = t0 + t1 + t2 + t3;
    float qq = t0*t0 + t1*t1 + t2*t2 + t3*t3;
    #pragma unroll
    for (int off = 32; off; off >>= 1) {
        s  += __shfl_xor(s, off);
        qq += __shfl_xor(qq, off);
    }
    __shared__ float red[8];
    const int wv = tid >> 6, ln = tid & 63;
    if (ln == 0) { red[wv] = s; red[wv + 4] = qq; }
    __syncthreads();
    s  = red[0] + red[1] + red[2] + red[3];
    qq = red[4] + red[5] + red[6] + red[7];
    const float mean = s * (1.0f / D_);
    const float var  = qq * (1.0f / D_) - mean * mean;
    const float rs   = rsqrtf(var + 1e-5f);
    const int c = tid * 4;
    float4 gv = *(const float4*)(g + c);
    float4 bv = *(const float4*)(beta + c);
    float o0 = (t0 - mean) * rs * gv.x + bv.x;
    float o1 = (t1 - mean) * rs * gv.y + bv.y;
    float o2 = (t2 - mean) * rs * gv.z + bv.z;
    float o3 = (t3 - mean) * rs * gv.w + bv.w;
    if (FINAL) {
        float4 o; o.x = o0; o.y = o1; o.z = o2; o.w = o3;
        *(float4*)(outF + base) = o;
    } else {
        b16x4 b; b[0] = (bf16_t)o0; b[1] = (bf16_t)o1; b[2] = (bf16_t)o2; b[3] = (bf16_t)o3;
        *(b16x4*)(outB + base) = b;
    }
}

extern "C" void kernel_launch(void* const* d_in, const int* in_sizes, int n_in,
                              void* d_out, int out_size, void* d_ws, size_t ws_size,
                              hipStream_t stream)
{
    const float* X    = (const float*)d_in[0];
    const unsigned char* mask = (const unsigned char*)d_in[1];
    const float* pe   = (const float*)d_in[2];
    const float* Wq   = (const float*)d_in[3];
    const float* Wk   = (const float*)d_in[4];
    const float* Wv   = (const float*)d_in[5];
    const float* bq   = (const float*)d_in[6];
    const float* bk   = (const float*)d_in[7];
    const float* bv   = (const float*)d_in[8];
    const float* Wo   = (const float*)d_in[9];
    const float* bo   = (const float*)d_in[10];
    const float* g1   = (const float*)d_in[11];
    const float* be1  = (const float*)d_in[12];
    const float* W1   = (const float*)d_in[13];
    const float* b1   = (const float*)d_in[14];
    const float* W2   = (const float*)d_in[15];
    const float* b2   = (const float*)d_in[16];
    const float* g2   = (const float*)d_in[17];
    const float* be2  = (const float*)d_in[18];

    // one-time: allow 128 KB dynamic LDS on the GEMM instantiations
    static int s_attr = [](){
        (void)hipFuncSetAttribute(reinterpret_cast<const void*>(&k_g256<0>),
                                  hipFuncAttributeMaxDynamicSharedMemorySize, 131072);
        (void)hipFuncSetAttribute(reinterpret_cast<const void*>(&k_g256<1>),
                                  hipFuncAttributeMaxDynamicSharedMemorySize, 131072);
        (void)hipFuncSetAttribute(reinterpret_cast<const void*>(&k_g256<2>),
                                  hipFuncAttributeMaxDynamicSharedMemorySize, 131072);
        return 0;
    }();
    (void)s_attr;

    char* ws = (char*)d_ws;
    bf16_t* WqkvT = (bf16_t*)(ws + OFF_WQKVT);
    bf16_t* WoT   = (bf16_t*)(ws + OFF_WOT);
    bf16_t* W1T   = (bf16_t*)(ws + OFF_W1T);
    bf16_t* W2T   = (bf16_t*)(ws + OFF_W2T);
    float*  bqkv  = (float*) (ws + OFF_BQKV);
    bf16_t* Xb    = (bf16_t*)(ws + OFF_XB);
    float*  Y     = (float*)d_out;            // d_out doubles as fp32 GEMM-out scratch

    const bool big = ws_size >= (size_t)234881024;

    // 1. Xb = bf16(X + pe)
    k_add_pe<<<MTOT * D_ / 1024, 256, 0, stream>>>(X, pe, Xb);

    // 2. fused weight prep
    k_prep<<<12300, 256, 0, stream>>>(Wq, Wk, Wv, Wo, W1, W2, bq, bk, bv,
                                      WqkvT, WoT, W1T, W2T, bqkv);

    if (big) {
        bf16_t* ctx  = (bf16_t*)(ws + OFF_B);              // 64 MB [96,160)
        bf16_t* qkvc = (bf16_t*)(ws + OFF_B + 67108864);   // 50 MB [160,210.3)
        // 3. QKV + attention in 2-batch chunks (8192 rows)
        for (int c = 0; c < 4; ++c) {
            const size_t r0 = (size_t)c * 8192;
            k_g256<1><<<dim3(3072/256, 8192/256), 512, 131072, stream>>>(
                Xb + r0*D_, WqkvT, bqkv, qkvc, 3072, 1024);
            k_attn<<<8192*H_/4, 256, 0, stream>>>(qkvc, mask + r0, ctx + r0*D_);
        }
        // 4. Y = ctx @ Wo + bo (fp32, into d_out)
        k_g256<0><<<dim3(1024/256, MTOT/256), 512, 131072, stream>>>(ctx, WoT, bo, Y, 1024, 1024);
        // 5. X1 = LN(Xb + Y) -> Xb (in-place bf16)
        k_res_ln<0><<<MTOT, 256, 0, stream>>>(Xb, Y, g1, be1, Xb, nullptr);
        // 6. FFN in two 16K-row chunks
        bf16_t* hb = (bf16_t*)(ws + OFF_B);                // 128 MB [96,224)
        for (int c = 0; c < 2; ++c) {
            const size_t r0 = (size_t)c * 16384;
            k_g256<2><<<dim3(NFF/256, 16384/256), 512, 131072, stream>>>(
                Xb + r0*D_, W1T, b1, hb, NFF, 1024);
            k_g256<0><<<dim3(1024/256, 16384/256), 512, 131072, stream>>>(
                hb, W2T, b2, Y + r0*D_, 1024, NFF);
        }
        // 7. out = LN(X1 + Y) -> fp32 d_out (in-place over Y)
        k_res_ln<1><<<MTOT, 256, 0, stream>>>(Xb, Y, g2, be2, nullptr, (float*)d_out);
    } else {
        bf16_t* qkvc = (bf16_t*)(ws + OFF_B);              // 24 MB [96,120)
        bf16_t* ctxc = (bf16_t*)(ws + OFF_B + 25165824);   //  8 MB [120,128)
        for (int b = 0; b < B_; ++b) {
            const size_t r0 = (size_t)b * L_;
            k_g256<1><<<dim3(3072/256, L_/256), 512, 131072, stream>>>(
                Xb + r0*D_, WqkvT, bqkv, qkvc, 3072, 1024);
            k_attn<<<L_*H_/4, 256, 0, stream>>>(qkvc, mask + r0, ctxc);
            k_g256<0><<<dim3(1024/256, L_/256), 512, 131072, stream>>>(
                ctxc, WoT, bo, Y + r0*D_, 1024, 1024);
        }
        k_res_ln<0><<<MTOT, 256, 0, stream>>>(Xb, Y, g1, be1, Xb, nullptr);
        bf16_t* hb = (bf16_t*)(ws + OFF_B);                // 32 MB [96,128)
        for (int c = 0; c < 8; ++c) {
            const size_t r0 = (size_t)c * L_;
            k_g256<2><<<dim3(NFF/256, L_/256), 512, 131072, stream>>>(
                Xb + r0*D_, W1T, b1, hb, NFF, 1024);
            k_g256<0><<<dim3(1024/256, L_/256), 512, 131072, stream>>>(
                hb, W2T, b2, Y + r0*D_, 1024, NFF);
        }
        k_res_ln<1><<<MTOT, 256, 0, stream>>>(Xb, Y, g2, be2, nullptr, (float*)d_out);
    }
}